// Round 1
// baseline (3668.279 us; speedup 1.0000x reference)
//
#include <hip/hip_runtime.h>
#include <cstddef>

// Problem constants
#define Bq   256
#define Sq   2048
#define Iq   128
#define Hq   32
#define THq  96      // 3H
#define Kq   64
#define Oq   256
#define Mq   3

// d_out layout: outputs (B*S*O floats) then hiddens (B*S*H floats)
#define OUT_HID_OFF 134217728ull     // B*S*O = 256*2048*256
// GI overlay: inside outputs[b] region, occupying rows 1280..2047
#define GI_BSTRIDE  524288ull        // S*O floats per batch in outputs
#define GI_OFF      327680ull        // 524288 - S*96

// ---------------------------------------------------------------------------
// Kernel 1: GI[b][s][j] = b_ih[j] + sum_i inputs[b][s][i] * W_ih[j][i]
// One thread per (b,s) row. acc[96] registers, x streamed in 32-float chunks,
// j-loop fully unrolled INSIDE a rolled c-loop (code ~34KB, fits i-cache once).
// W_ih broadcast from LDS. ~150 VGPR -> 2 blocks/CU.
// ---------------------------------------------------------------------------
__global__ __launch_bounds__(256, 2) void gi_gemm_kernel(
    const float* __restrict__ x, const float* __restrict__ Wih,
    const float* __restrict__ bih, float* __restrict__ gi_base)
{
    __shared__ __align__(16) float Wl[THq * Iq];   // 48 KB
    __shared__ __align__(16) float Bl[THq];
    const int tid = threadIdx.x;

    {
        const float4* Wg4 = (const float4*)Wih;
        float4* Wl4 = (float4*)Wl;
        #pragma unroll
        for (int i = 0; i < 12; ++i)
            Wl4[tid + 256 * i] = Wg4[tid + 256 * i];
        if (tid < THq) Bl[tid] = bih[tid];
    }
    __syncthreads();

    const int r = blockIdx.x * 256 + tid;           // row in [0, B*S)
    const int b = r >> 11;
    const int s = r & 2047;
    const float4* xg = (const float4*)(x + (size_t)r * Iq);

    float acc[THq];
    #pragma unroll
    for (int j4 = 0; j4 < 24; ++j4) {
        float4 bv = ((const float4*)Bl)[j4];
        acc[4*j4+0] = bv.x; acc[4*j4+1] = bv.y;
        acc[4*j4+2] = bv.z; acc[4*j4+3] = bv.w;
    }

    #pragma unroll 1
    for (int c = 0; c < 4; ++c) {                   // k-chunks of 32 floats
        float4 xv[8];
        #pragma unroll
        for (int i = 0; i < 8; ++i) xv[i] = xg[c * 8 + i];
        #pragma unroll
        for (int j = 0; j < THq; ++j) {
            const float4* w4 = (const float4*)(Wl + j * Iq) + c * 8;
            float p0 = acc[j], p1 = 0.f, p2 = 0.f, p3 = 0.f;
            #pragma unroll
            for (int i = 0; i < 8; ++i) {
                float4 w  = w4[i];
                float4 xx = xv[i];
                p0 = fmaf(xx.x, w.x, p0);
                p1 = fmaf(xx.y, w.y, p1);
                p2 = fmaf(xx.z, w.z, p2);
                p3 = fmaf(xx.w, w.w, p3);
            }
            acc[j] = (p0 + p1) + (p2 + p3);
        }
    }

    float* outp = gi_base + (size_t)b * GI_BSTRIDE + GI_OFF + (size_t)s * THq;
    float4* o4 = (float4*)outp;
    #pragma unroll
    for (int j4 = 0; j4 < 24; ++j4)
        o4[j4] = make_float4(acc[4*j4+0], acc[4*j4+1], acc[4*j4+2], acc[4*j4+3]);
}

// ---------------------------------------------------------------------------
// Kernel 2: fused scan. 1 block per batch, 128 threads:
//   wave 0 (tid 0..63)  : GRU cell for step t
//   wave 1 (tid 64..127): attention + output for t-1, kv/A writes for t-1 < 3
// LDS-only barrier (lgkmcnt drain, NO vmcnt drain): global stores never sit
// on the critical path. Scores computed as h.A_m + c_m (A_m = Wq^T K_m cached
// in LDS, updated only at t<3) -> no per-step cross-lane reduction.
// ---------------------------------------------------------------------------
__device__ __forceinline__ void lds_barrier() {
    __builtin_amdgcn_sched_barrier(0);
    asm volatile("s_waitcnt lgkmcnt(0)" ::: "memory");
    __builtin_amdgcn_s_barrier();
    __builtin_amdgcn_sched_barrier(0);
}

__device__ __forceinline__ float sigmoid_f(float x) {
    return __builtin_amdgcn_rcpf(1.f + __expf(-x));
}
__device__ __forceinline__ float tanh_f(float x) {
    x = fminf(fmaxf(x, -30.f), 30.f);
    float e = __expf(-2.f * x);
    return fmaf(2.f, __builtin_amdgcn_rcpf(1.f + e), -1.f);   // 2/(1+e) - 1
}

__global__ __launch_bounds__(128) void scan_kernel(
    const float* __restrict__ Whh, const float* __restrict__ bhh,
    const float* __restrict__ Wk,  const float* __restrict__ bk,
    const float* __restrict__ Wq,  const float* __restrict__ bq,
    const float* __restrict__ Wv,  const float* __restrict__ bv,
    float* __restrict__ dout)
{
    const int tid = threadIdx.x;
    const int b = blockIdx.x;

    __shared__ __align__(16) float hbuf[2][Hq];
    __shared__ __align__(16) float keysS[Mq][Kq];
    __shared__ __align__(16) float valsS[Mq][Oq];
    __shared__ __align__(16) float As[Mq][36];   // [m][0..31]=Wq^T K_m, [m][32]=bq.K_m

    if (tid < Hq) { hbuf[0][tid] = 0.f; hbuf[1][tid] = 0.f; }
    for (int i = tid; i < Mq * Kq; i += 128) ((float*)keysS)[i] = 0.f;
    for (int i = tid; i < Mq * Oq; i += 128) ((float*)valsS)[i] = 0.f;
    for (int i = tid; i < Mq * 36; i += 128) ((float*)As)[i] = 0.f;

    const float* gi_row = dout + (size_t)b * GI_BSTRIDE + GI_OFF;
    float* out_o = dout + (size_t)b * GI_BSTRIDE;                 // outputs[b]
    float* out_h = dout + OUT_HID_OFF + (size_t)b * (Sq * Hq);    // hiddens[b]

    if (tid < 64) {
        // ------------------------- cell wave -------------------------
        // vmcnt stream contains ONLY gi prefetch loads (no stores) -> counted
        // waits never gate on store acks.
        const int l = tid;
        const bool lo = (l < Hq);
        float wa[Hq], wb[Hq];
        #pragma unroll
        for (int kk = 0; kk < Hq; ++kk) wa[kk] = Whh[l * Hq + kk];
        #pragma unroll
        for (int kk = 0; kk < Hq; ++kk) wb[kk] = lo ? Whh[(64 + l) * Hq + kk] : 0.f;
        const float ba = bhh[l];
        const float bb = lo ? bhh[64 + l] : 0.f;
        float h_old = 0.f;

        const int PF = 4;
        float ga[4], gb[4];
        #pragma unroll
        for (int d = 0; d < PF; ++d) {
            ga[d] = gi_row[(size_t)d * THq + l];
            gb[d] = lo ? gi_row[(size_t)d * THq + 64 + l] : 0.f;
        }

        for (int t = 0; t <= Sq; ++t) {
            lds_barrier();
            if (t < Sq) {
                const float gia = ga[0];
                const float gib = gb[0];
                #pragma unroll
                for (int d = 0; d < PF - 1; ++d) { ga[d] = ga[d+1]; gb[d] = gb[d+1]; }
                const int tt = t + PF;
                if (tt < Sq) {
                    ga[PF-1] = gi_row[(size_t)tt * THq + l];
                    gb[PF-1] = lo ? gi_row[(size_t)tt * THq + 64 + l] : 0.f;
                } else { ga[PF-1] = 0.f; gb[PF-1] = 0.f; }

                const float4* h4 = (const float4*)hbuf[(t + 1) & 1];  // h_{t-1}
                float gha = ba, ghb = bb;
                #pragma unroll
                for (int kk = 0; kk < 8; ++kk) {
                    float4 hv = h4[kk];
                    gha = fmaf(hv.x, wa[4*kk+0], gha);
                    gha = fmaf(hv.y, wa[4*kk+1], gha);
                    gha = fmaf(hv.z, wa[4*kk+2], gha);
                    gha = fmaf(hv.w, wa[4*kk+3], gha);
                    ghb = fmaf(hv.x, wb[4*kk+0], ghb);
                    ghb = fmaf(hv.y, wb[4*kk+1], ghb);
                    ghb = fmaf(hv.z, wb[4*kk+2], ghb);
                    ghb = fmaf(hv.w, wb[4*kk+3], ghb);
                }
                const float xa = gia + gha;              // r-pre (l<32) / z-pre (l>=32)
                const float xz = __shfl(xa, l + 32, 64); // lanes <32 pull z-pre
                if (lo) {
                    const float rr = sigmoid_f(xa);
                    const float zz = sigmoid_f(xz);
                    const float nn = tanh_f(gib + rr * ghb);
                    const float hn = (1.f - zz) * nn + zz * h_old;
                    h_old = hn;
                    hbuf[t & 1][l] = hn;
                }
            }
        }
    } else {
        // ------------------------- attention wave -------------------------
        const int k = tid - 64;          // 0..63

        for (int t = 0; t <= Sq; ++t) {
            lds_barrier();
            if (t >= 1) {
                const int tp = t - 1;
                const float4* h4 = (const float4*)hbuf[tp & 1];
                float4 hr[8];
                #pragma unroll
                for (int kk = 0; kk < 8; ++kk) hr[kk] = h4[kk];

                // scores: s_m = h . A_m + c_m  (lane-local, no reduction)
                float sm[3];
                #pragma unroll
                for (int m = 0; m < Mq; ++m) {
                    const float4* Am4 = (const float4*)As[m];
                    float p0 = As[m][32], p1 = 0.f, p2 = 0.f, p3 = 0.f;
                    #pragma unroll
                    for (int kk = 0; kk < 8; ++kk) {
                        float4 av = Am4[kk];
                        float4 hv = hr[kk];
                        p0 = fmaf(hv.x, av.x, p0);
                        p1 = fmaf(hv.y, av.y, p1);
                        p2 = fmaf(hv.z, av.z, p2);
                        p3 = fmaf(hv.w, av.w, p3);
                    }
                    sm[m] = (p0 + p1) + (p2 + p3);
                }

                const int v = tp < Mq ? tp : Mq;
                float w0 = 0.f, w1 = 0.f, w2 = 0.f;
                if (v > 0) {
                    float mx = sm[0];
                    if (v > 1) mx = fmaxf(mx, sm[1]);
                    if (v > 2) mx = fmaxf(mx, sm[2]);
                    const float e0 = __expf(sm[0] - mx);
                    const float e1 = (v > 1) ? __expf(sm[1] - mx) : 0.f;
                    const float e2 = (v > 2) ? __expf(sm[2] - mx) : 0.f;
                    const float inv = __builtin_amdgcn_rcpf(e0 + e1 + e2);
                    w0 = e0 * inv; w1 = e1 * inv; w2 = e2 * inv;
                }
                // retrieved: lane k owns outputs 4k..4k+3
                const float4 a0 = ((const float4*)valsS[0])[k];
                const float4 a1 = ((const float4*)valsS[1])[k];
                const float4 a2 = ((const float4*)valsS[2])[k];
                float4 accv;
                accv.x = w0*a0.x + w1*a1.x + w2*a2.x;
                accv.y = w0*a0.y + w1*a1.y + w2*a2.y;
                accv.z = w0*a0.z + w1*a1.z + w2*a2.z;
                accv.w = w0*a0.w + w1*a1.w + w2*a2.w;
                ((float4*)(out_o + (size_t)tp * Oq))[k] = accv;           // fire & forget
                if (k < 8)
                    ((float4*)(out_h + (size_t)tp * Hq))[k] = hr[k];      // fire & forget

                // memory write (only first M steps) + A/c refresh
                if (tp < Mq) {
                    const float4* wk4 = (const float4*)(Wk + k * Hq);
                    float kv = bk[k];
                    #pragma unroll
                    for (int kk = 0; kk < 8; ++kk) {
                        float4 w = wk4[kk]; float4 hv = hr[kk];
                        kv = fmaf(hv.x, w.x, kv);
                        kv = fmaf(hv.y, w.y, kv);
                        kv = fmaf(hv.z, w.z, kv);
                        kv = fmaf(hv.w, w.w, kv);
                    }
                    keysS[tp][k] = kv;
                    #pragma unroll
                    for (int j = 0; j < 4; ++j) {
                        const int o = 4 * k + j;
                        const float4* wv4 = (const float4*)(Wv + o * Hq);
                        float vv = bv[o];
                        #pragma unroll
                        for (int kk = 0; kk < 8; ++kk) {
                            float4 w = wv4[kk]; float4 hv = hr[kk];
                            vv = fmaf(hv.x, w.x, vv);
                            vv = fmaf(hv.y, w.y, vv);
                            vv = fmaf(hv.z, w.z, vv);
                            vv = fmaf(hv.w, w.w, vv);
                        }
                        valsS[tp][o] = vv;
                    }
                    // c_m = sum_k bq[k] * K_m[k]  (butterfly; only 3x total)
                    float cm = bq[k] * kv;
                    #pragma unroll
                    for (int off = 1; off < 64; off <<= 1)
                        cm += __shfl_xor(cm, off, 64);
                    if (k == 0) As[tp][32] = cm;
                    // A_m[j] = sum_k Wq[k][j] * K_m[k]  (lanes j<32; only 3x total)
                    if (k < Hq) {
                        float a = 0.f;
                        #pragma unroll
                        for (int kk = 0; kk < Kq; ++kk)
                            a = fmaf(Wq[kk * Hq + k], keysS[tp][kk], a);
                        As[tp][k] = a;
                    }
                }
            }
        }
    }
}

// ---------------------------------------------------------------------------
extern "C" void kernel_launch(void* const* d_in, const int* in_sizes, int n_in,
                              void* d_out, int out_size, void* d_ws, size_t ws_size,
                              hipStream_t stream) {
    const float* inputs = (const float*)d_in[0];
    const float* W_ih   = (const float*)d_in[1];
    const float* W_hh   = (const float*)d_in[2];
    const float* b_ih   = (const float*)d_in[3];
    const float* b_hh   = (const float*)d_in[4];
    const float* Wk     = (const float*)d_in[5];
    const float* bk     = (const float*)d_in[6];
    const float* Wq     = (const float*)d_in[7];
    const float* bq     = (const float*)d_in[8];
    const float* Wv     = (const float*)d_in[9];
    const float* bv     = (const float*)d_in[10];
    float* out = (float*)d_out;

    // Kernel 1: GI GEMM into the overlay region of d_out (tail of outputs[b])
    gi_gemm_kernel<<<(Bq * Sq) / 256, 256, 0, stream>>>(inputs, W_ih, b_ih, out);
    // Kernel 2: fused sequential scan + attention + output/hidden stores
    scan_kernel<<<Bq, 128, 0, stream>>>(W_hh, b_hh, Wk, bk, Wq, bq, Wv, bv, out);
}

// Round 2
// 2307.138 us; speedup vs baseline: 1.5900x; 1.5900x over previous
//
#include <hip/hip_runtime.h>
#include <cstddef>

// Problem constants
#define Bq   256
#define Sq   2048
#define Iq   128
#define Hq   32
#define THq  96      // 3H
#define Kq   64
#define Oq   256
#define Mq   3

// d_out layout: outputs (B*S*O floats) then hiddens (B*S*H floats)
#define OUT_HID_OFF 134217728ull     // B*S*O = 256*2048*256
// GI overlay: inside outputs[b] region, occupying rows 1280..2047
#define GI_BSTRIDE  524288ull        // S*O floats per batch in outputs
#define GI_OFF      327680ull        // 524288 - S*96

// ---------------------------------------------------------------------------
// Kernel 1: GI[b][s][j] = b_ih[j] + sum_i inputs[b][s][i] * W_ih[j][i]
// No LDS. W_ih is read through BLOCK-UNIFORM addresses (jbase from blockIdx
// parity) -> compiler emits s_load into SGPRs: one 128B fetch per WAVE (not
// per lane), scalar pipe runs in parallel with the VALU FMAs. j split 48/48
// keeps the hot body ~15KB (fits I$) and acc[48]+xv[8] ~100 VGPR -> 4+/SIMD.
// ---------------------------------------------------------------------------
__global__ __launch_bounds__(256) void gi_gemm_kernel(
    const float* __restrict__ x, const float* __restrict__ Wih,
    const float* __restrict__ bih, float* __restrict__ gi_base)
{
    const int tid   = threadIdx.x;
    const int jbase = (blockIdx.x & 1) * 48;            // wave-uniform (scalar)
    const int r     = (blockIdx.x >> 1) * 256 + tid;    // row in [0, B*S)
    const int b     = r >> 11;
    const int s     = r & 2047;

    const float4* xg = (const float4*)(x + (size_t)r * Iq);

    float acc[48];
    #pragma unroll
    for (int j = 0; j < 48; ++j) acc[j] = bih[jbase + j];   // uniform -> s_load

    #pragma unroll 1
    for (int c = 0; c < 4; ++c) {                 // K chunks of 32 floats
        float4 xv[8];
        #pragma unroll
        for (int i = 0; i < 8; ++i) xv[i] = xg[c * 8 + i];
        #pragma unroll
        for (int j = 0; j < 48; ++j) {
            const float4* w4 = (const float4*)(Wih + (size_t)(jbase + j) * Iq) + c * 8;
            float p0 = acc[j], p1 = 0.f, p2 = 0.f, p3 = 0.f;
            #pragma unroll
            for (int i = 0; i < 8; ++i) {
                float4 w  = w4[i];                // uniform addr -> SGPR operand
                float4 xx = xv[i];
                p0 = fmaf(xx.x, w.x, p0);
                p1 = fmaf(xx.y, w.y, p1);
                p2 = fmaf(xx.z, w.z, p2);
                p3 = fmaf(xx.w, w.w, p3);
            }
            acc[j] = (p0 + p1) + (p2 + p3);
        }
    }

    float* outp = gi_base + (size_t)b * GI_BSTRIDE + GI_OFF + (size_t)s * THq + jbase;
    float4* o4 = (float4*)outp;
    #pragma unroll
    for (int j4 = 0; j4 < 12; ++j4)
        o4[j4] = make_float4(acc[4*j4+0], acc[4*j4+1], acc[4*j4+2], acc[4*j4+3]);
}

// ---------------------------------------------------------------------------
// Kernel 2: fused scan. 1 block per batch, 128 threads:
//   wave 0 (tid 0..63)  : GRU cell for step t, stores hiddens (fire&forget)
//   wave 1 (tid 64..127): attention + output for t-1, kv/A writes for t-1 < 3
// LDS-only barrier (lgkmcnt drain, NO vmcnt drain): global stores never sit
// on the critical path. NO sched_barrier (m141 lesson) - the "memory" clobber
// + s_barrier intrinsic already order all DS ops. NO runtime-indexed register
// arrays anywhere (rule #20).
// ---------------------------------------------------------------------------
__device__ __forceinline__ void lds_barrier() {
    asm volatile("s_waitcnt lgkmcnt(0)" ::: "memory");
    __builtin_amdgcn_s_barrier();
}

__device__ __forceinline__ float sigmoid_f(float x) {
    return __builtin_amdgcn_rcpf(1.f + __expf(-x));
}
__device__ __forceinline__ float tanh_f(float x) {
    x = fminf(fmaxf(x, -30.f), 30.f);
    float e = __expf(-2.f * x);
    return fmaf(2.f, __builtin_amdgcn_rcpf(1.f + e), -1.f);   // 2/(1+e) - 1
}

__global__ __launch_bounds__(128) void scan_kernel(
    const float* __restrict__ Whh, const float* __restrict__ bhh,
    const float* __restrict__ Wk,  const float* __restrict__ bk,
    const float* __restrict__ Wq,  const float* __restrict__ bq,
    const float* __restrict__ Wv,  const float* __restrict__ bv,
    float* __restrict__ dout)
{
    const int tid = threadIdx.x;
    const int b = blockIdx.x;

    __shared__ __align__(16) float hbuf[2][Hq];
    __shared__ __align__(16) float keysS[Mq][Kq];
    __shared__ __align__(16) float valsS[Mq][Oq];
    __shared__ __align__(16) float As[Mq][36];   // [m][0..31]=Wq^T K_m, [m][32]=bq.K_m

    if (tid < Hq) { hbuf[0][tid] = 0.f; hbuf[1][tid] = 0.f; }
    for (int i = tid; i < Mq * Kq; i += 128) ((float*)keysS)[i] = 0.f;
    for (int i = tid; i < Mq * Oq; i += 128) ((float*)valsS)[i] = 0.f;
    for (int i = tid; i < Mq * 36; i += 128) ((float*)As)[i] = 0.f;

    const float* gi_row = dout + (size_t)b * GI_BSTRIDE + GI_OFF;
    float* out_o = dout + (size_t)b * GI_BSTRIDE;                 // outputs[b]
    float* out_h = dout + OUT_HID_OFF + (size_t)b * (Sq * Hq);    // hiddens[b]

    if (tid < 64) {
        // ------------------------- cell wave -------------------------
        const int l = tid;
        const bool lo = (l < Hq);
        float wa[Hq], wb[Hq];
        #pragma unroll
        for (int kk = 0; kk < Hq; ++kk) wa[kk] = Whh[l * Hq + kk];
        #pragma unroll
        for (int kk = 0; kk < Hq; ++kk) wb[kk] = lo ? Whh[(64 + l) * Hq + kk] : 0.f;
        const float ba = bhh[l];
        const float bb = lo ? bhh[64 + l] : 0.f;
        float h_old = 0.f;

        const int PF = 4;
        float ga[4], gb[4];
        #pragma unroll
        for (int d = 0; d < PF; ++d) {
            ga[d] = gi_row[(size_t)d * THq + l];
            gb[d] = lo ? gi_row[(size_t)d * THq + 64 + l] : 0.f;
        }

        for (int t = 0; t <= Sq; ++t) {
            lds_barrier();
            if (t < Sq) {
                const float gia = ga[0];
                const float gib = gb[0];
                #pragma unroll
                for (int d = 0; d < PF - 1; ++d) { ga[d] = ga[d+1]; gb[d] = gb[d+1]; }
                const int tt = t + PF;
                if (tt < Sq) {
                    ga[PF-1] = gi_row[(size_t)tt * THq + l];
                    gb[PF-1] = lo ? gi_row[(size_t)tt * THq + 64 + l] : 0.f;
                } else { ga[PF-1] = 0.f; gb[PF-1] = 0.f; }

                const float4* h4 = (const float4*)hbuf[(t + 1) & 1];  // h_{t-1}
                float gha = ba, ghb = bb;
                #pragma unroll
                for (int kk = 0; kk < 8; ++kk) {
                    float4 hv = h4[kk];
                    gha = fmaf(hv.x, wa[4*kk+0], gha);
                    gha = fmaf(hv.y, wa[4*kk+1], gha);
                    gha = fmaf(hv.z, wa[4*kk+2], gha);
                    gha = fmaf(hv.w, wa[4*kk+3], gha);
                    ghb = fmaf(hv.x, wb[4*kk+0], ghb);
                    ghb = fmaf(hv.y, wb[4*kk+1], ghb);
                    ghb = fmaf(hv.z, wb[4*kk+2], ghb);
                    ghb = fmaf(hv.w, wb[4*kk+3], ghb);
                }
                const float xa = gia + gha;              // r-pre (l<32) / z-pre (l>=32)
                const float xz = __shfl(xa, l + 32, 64); // lanes <32 pull z-pre
                if (lo) {
                    const float rr = sigmoid_f(xa);
                    const float zz = sigmoid_f(xz);
                    const float nn = tanh_f(gib + rr * ghb);
                    const float hn = (1.f - zz) * nn + zz * h_old;
                    h_old = hn;
                    hbuf[t & 1][l] = hn;
                    out_h[(size_t)t * Hq + l] = hn;      // fire & forget (no vmcnt drain)
                }
            }
        }
    } else {
        // ------------------------- attention wave -------------------------
        const int k = tid - 64;          // 0..63

        for (int t = 0; t <= Sq; ++t) {
            lds_barrier();
            if (t >= 1) {
                const int tp = t - 1;
                const float4* h4 = (const float4*)hbuf[tp & 1];
                float4 hr[8];
                #pragma unroll
                for (int kk = 0; kk < 8; ++kk) hr[kk] = h4[kk];   // static idx only

                // scores: s_m = h . A_m + c_m  (lane-local, no reduction)
                float sm[3];
                #pragma unroll
                for (int m = 0; m < Mq; ++m) {
                    const float4* Am4 = (const float4*)As[m];
                    float p0 = As[m][32], p1 = 0.f, p2 = 0.f, p3 = 0.f;
                    #pragma unroll
                    for (int kk = 0; kk < 8; ++kk) {
                        float4 av = Am4[kk];
                        float4 hv = hr[kk];
                        p0 = fmaf(hv.x, av.x, p0);
                        p1 = fmaf(hv.y, av.y, p1);
                        p2 = fmaf(hv.z, av.z, p2);
                        p3 = fmaf(hv.w, av.w, p3);
                    }
                    sm[m] = (p0 + p1) + (p2 + p3);
                }

                const int v = tp < Mq ? tp : Mq;
                float w0 = 0.f, w1 = 0.f, w2 = 0.f;
                if (v > 0) {
                    float mx = sm[0];
                    if (v > 1) mx = fmaxf(mx, sm[1]);
                    if (v > 2) mx = fmaxf(mx, sm[2]);
                    const float e0 = __expf(sm[0] - mx);
                    const float e1 = (v > 1) ? __expf(sm[1] - mx) : 0.f;
                    const float e2 = (v > 2) ? __expf(sm[2] - mx) : 0.f;
                    const float inv = __builtin_amdgcn_rcpf(e0 + e1 + e2);
                    w0 = e0 * inv; w1 = e1 * inv; w2 = e2 * inv;
                }
                // retrieved: lane k owns outputs 4k..4k+3
                const float4 a0 = ((const float4*)valsS[0])[k];
                const float4 a1 = ((const float4*)valsS[1])[k];
                const float4 a2 = ((const float4*)valsS[2])[k];
                float4 accv;
                accv.x = w0*a0.x + w1*a1.x + w2*a2.x;
                accv.y = w0*a0.y + w1*a1.y + w2*a2.y;
                accv.z = w0*a0.z + w1*a1.z + w2*a2.z;
                accv.w = w0*a0.w + w1*a1.w + w2*a2.w;
                ((float4*)(out_o + (size_t)tp * Oq))[k] = accv;    // fire & forget

                // memory write (only first M steps) + A/c refresh
                if (tp < Mq) {
                    const float4* wk4 = (const float4*)(Wk + k * Hq);
                    float kv = bk[k];
                    #pragma unroll
                    for (int kk = 0; kk < 8; ++kk) {
                        float4 w = wk4[kk]; float4 hv = hr[kk];
                        kv = fmaf(hv.x, w.x, kv);
                        kv = fmaf(hv.y, w.y, kv);
                        kv = fmaf(hv.z, w.z, kv);
                        kv = fmaf(hv.w, w.w, kv);
                    }
                    keysS[tp][k] = kv;
                    #pragma unroll
                    for (int j = 0; j < 4; ++j) {
                        const int o = 4 * k + j;
                        const float4* wv4 = (const float4*)(Wv + o * Hq);
                        float vv = bv[o];
                        #pragma unroll
                        for (int kk = 0; kk < 8; ++kk) {
                            float4 w = wv4[kk]; float4 hv = hr[kk];
                            vv = fmaf(hv.x, w.x, vv);
                            vv = fmaf(hv.y, w.y, vv);
                            vv = fmaf(hv.z, w.z, vv);
                            vv = fmaf(hv.w, w.w, vv);
                        }
                        valsS[tp][o] = vv;
                    }
                    // c_m = sum_k bq[k] * K_m[k]  (butterfly; only 3x total)
                    float cm = bq[k] * kv;
                    #pragma unroll
                    for (int off = 1; off < 64; off <<= 1)
                        cm += __shfl_xor(cm, off, 64);
                    if (k == 0) As[tp][32] = cm;
                    // A_m[j] = sum_k Wq[k][j] * K_m[k]  (lanes j<32; only 3x total)
                    if (k < Hq) {
                        float a = 0.f;
                        #pragma unroll
                        for (int kk = 0; kk < Kq; ++kk)
                            a = fmaf(Wq[kk * Hq + k], keysS[tp][kk], a);
                        As[tp][k] = a;
                    }
                }
            }
        }
    }
}

// ---------------------------------------------------------------------------
extern "C" void kernel_launch(void* const* d_in, const int* in_sizes, int n_in,
                              void* d_out, int out_size, void* d_ws, size_t ws_size,
                              hipStream_t stream) {
    const float* inputs = (const float*)d_in[0];
    const float* W_ih   = (const float*)d_in[1];
    const float* W_hh   = (const float*)d_in[2];
    const float* b_ih   = (const float*)d_in[3];
    const float* b_hh   = (const float*)d_in[4];
    const float* Wk     = (const float*)d_in[5];
    const float* bk     = (const float*)d_in[6];
    const float* Wq     = (const float*)d_in[7];
    const float* bq     = (const float*)d_in[8];
    const float* Wv     = (const float*)d_in[9];
    const float* bv     = (const float*)d_in[10];
    float* out = (float*)d_out;

    // Kernel 1: GI GEMM into the overlay region of d_out (tail of outputs[b])
    gi_gemm_kernel<<<(Bq * Sq) / 256 * 2, 256, 0, stream>>>(inputs, W_ih, b_ih, out);
    // Kernel 2: fused sequential scan + attention + output/hidden stores
    scan_kernel<<<Bq, 128, 0, stream>>>(W_hh, b_hh, Wk, bk, Wq, bq, Wv, bv, out);
}